// Round 4
// baseline (169.418 us; speedup 1.0000x reference)
//
#include <hip/hip_runtime.h>

#define BB 8
#define SS 4096
#define DD 768
#define EE 128
#define PP 8128   // E*(E-1)/2
#define MP 25
#define MT 3500
#define D4 192    // DD/4 float4 per row
#define NROWS_W  (BB*MT)   // 28000 words rows
#define NROWS_P  (BB*PP)   // 65024 pair rows (per head/tail)
#define NROWS_PR (BB*MP)   // 200 prompt rows
#define R_TOTAL  (NROWS_W + 2*NROWS_P + NROWS_PR)  // 158248

typedef float f32x4 __attribute__((ext_vector_type(4)));

// ---------------------------------------------------------------------------
// Kernel A: 24 blocks x 256. role = blk>>3, b = blk&7.
//   role 0: specials ballot-scan -> ws.pos[b][25], out1 (prompt mask)
//   role 1: word_mask (out3) + wordpos init + scatter
//   role 2: pair stable-partition -> ws.pairrec + out4 (pair_idx) + out5 (mask)
// All scalar/small outputs produced here so k_gather is a pure row copier.
// ---------------------------------------------------------------------------
__global__ __launch_bounds__(256) void k_prep(
    const int* __restrict__ ids, const float* __restrict__ adj,
    const int* __restrict__ wm, const int* __restrict__ tlen,
    float* __restrict__ out1, float* __restrict__ out3,
    float* __restrict__ out4, float* __restrict__ out5,
    int* __restrict__ wordpos, int* __restrict__ pairrec,
    int* __restrict__ pos)
{
    int blk = blockIdx.x;
    int role = blk >> 3, b = blk & 7;
    int t = threadIdx.x, wave = t >> 6, lane = t & 63;

    if (role == 0) {
        // ---- specials scan: 4 waves x 1024 tokens each ----
        __shared__ int pos_s[32];
        __shared__ int spos[4 * 32];
        __shared__ int wcnt[4];
        __shared__ int woff[5];
        if (t < 32) pos_s[t] = -1;
        __syncthreads();
        const int* row = ids + b * SS;
        int base = 0;
        for (int c = 0; c < 16; ++c) {
            int p = wave * 1024 + c * 64 + lane;
            bool s = (row[p] == 1);
            unsigned long long m = __ballot(s);
            if (s) {
                int sl = base + __popcll(m & ((1ull << lane) - 1ull));
                if (sl < 32) spos[wave * 32 + sl] = p;
            }
            base += __popcll(m);
        }
        if (lane == 0) wcnt[wave] = base;
        __syncthreads();
        if (t == 0) {
            int acc = 0;
            for (int w = 0; w < 4; ++w) { woff[w] = acc; acc += wcnt[w]; }
            woff[4] = acc;
        }
        __syncthreads();
        {
            int cnt = wcnt[wave]; if (cnt > 32) cnt = 32;
            if (lane < cnt) {
                int g = woff[wave] + lane;
                if (g < MP) pos_s[g] = spos[wave * 32 + lane];
            }
        }
        __syncthreads();
        if (t < MP) {
            pos[b * MP + t] = pos_s[t];
            out1[b * MP + t] = (t < woff[4]) ? 1.0f : 0.0f;
        }
    } else if (role == 1) {
        // ---- word_mask + wordpos init, then scatter (same block => ordered) ----
        int L = tlen[b];
        for (int i = t; i < MT; i += 256) {
            out3[b * MT + i] = (i < L) ? 1.0f : 0.0f;
            wordpos[b * MT + i] = -1;
        }
        __syncthreads();
        #pragma unroll 4
        for (int i = t; i < SS; i += 256) {
            int v = wm[b * SS + i];
            if (v > 0 && v <= MT) wordpos[b * MT + v - 1] = i;
        }
    } else {
        // ---- pair stable-partition: thread t owns 32 contiguous pairs ----
        __shared__ int wsum[4];
        int p0 = t * 32;
        bool act = p0 < PP;          // threads 254,255 idle
        int r0 = 0, c0 = 0;
        if (act) {
            int lo = 0, hi = EE - 2;
            while (lo < hi) {        // start(r) = r*(255-r)/2 <= p0
                int mid = (lo + hi + 1) >> 1;
                int st = mid * (2 * EE - 1 - mid) / 2;
                if (st <= p0) lo = mid; else hi = mid - 1;
            }
            r0 = lo;
            c0 = r0 + 1 + (p0 - r0 * (2 * EE - 1 - r0) / 2);
        }
        unsigned selmask = 0;
        int my = 0;
        {
            int rr = r0, cc = c0;
            for (int i = 0; i < 32; ++i) {
                if (act && p0 + i < PP) {
                    bool s = adj[((size_t)b * EE + rr) * EE + cc] > 0.5f;
                    selmask |= (unsigned)s << i;
                    my += s ? 1 : 0;
                    if (++cc == EE) { ++rr; cc = rr + 1; }
                }
            }
        }
        int inc = my;
        for (int off = 1; off < 64; off <<= 1) {
            int n = __shfl_up(inc, off);
            if (lane >= off) inc += n;
        }
        if (lane == 63) wsum[wave] = inc;
        __syncthreads();
        int wv_off = 0, K = 0;
        for (int w = 0; w < 4; ++w) {
            int s = wsum[w];
            if (w < wave) wv_off += s;
            K += s;
        }
        int selb = wv_off + inc - my;
        {
            int rr = r0, cc = c0;
            for (int i = 0; i < 32; ++i) {
                int p = p0 + i;
                if (act && p < PP) {
                    bool s = (selmask >> i) & 1u;
                    int q;
                    if (s) { q = selb; ++selb; }
                    else   { q = K + (p - selb); }
                    size_t oq = (size_t)b * PP + q;
                    pairrec[oq] = s ? (int)(0x80000000u | ((unsigned)rr << 8) | (unsigned)cc) : 0;
                    out4[oq * 2 + 0] = s ? (float)rr : -1.0f;
                    out4[oq * 2 + 1] = s ? (float)cc : -1.0f;
                    out5[oq]         = s ? 1.0f : 0.0f;
                    if (++cc == EE) { ++rr; cc = rr + 1; }
                }
            }
        }
    }
}

// ---------------------------------------------------------------------------
// Kernel B: pure row gather, one 768-f32 row per wave per iteration with the
// next row's 4-B index prefetched. Row space:
// [0,28000) words | [28000,93024) head | [93024,158048) tail | +200 prompts.
// ---------------------------------------------------------------------------
__device__ __forceinline__ int row_index(const int* __restrict__ wordpos,
                                         const int* __restrict__ pairrec,
                                         const int* __restrict__ pos, int row) {
    if (row < NROWS_W) return wordpos[row];
    if (row < NROWS_W + 2 * NROWS_P) {
        int idx2 = row - NROWS_W;
        int idx = (idx2 < NROWS_P) ? idx2 : idx2 - NROWS_P;
        return pairrec[idx];
    }
    return pos[row - (NROWS_W + 2 * NROWS_P)];
}

__global__ __launch_bounds__(256) void k_gather(
    const float* __restrict__ te, const float* __restrict__ sr,
    const int* __restrict__ wordpos, const int* __restrict__ pairrec,
    const int* __restrict__ pos,
    float* __restrict__ out0, float* __restrict__ out2,
    float* __restrict__ out6, float* __restrict__ out7)
{
    int gw = blockIdx.x * 4 + (threadIdx.x >> 6);
    int lane = threadIdx.x & 63;
    int nw = gridDim.x * 4;
    const f32x4* te4 = (const f32x4*)te;
    const f32x4* sr4 = (const f32x4*)sr;

    int row = gw;
    int iv = (row < R_TOTAL) ? row_index(wordpos, pairrec, pos, row) : 0;
    for (; row < R_TOTAL; row += nw) {
        int cur = iv;
        int nrow = row + nw;
        if (nrow < R_TOTAL) iv = row_index(wordpos, pairrec, pos, nrow);

        const f32x4* src4;
        f32x4* dst4;
        bool valid = true;
        bool stream_src = false;
        if (row < NROWS_W) {
            int b = row / MT;
            valid = (cur >= 0);
            src4 = te4 + ((size_t)(b * SS + (valid ? cur : 0))) * D4;
            dst4 = (f32x4*)out2 + (size_t)row * D4;
            stream_src = true;
        } else if (row < NROWS_W + 2 * NROWS_P) {
            int idx2 = row - NROWS_W;
            bool head = idx2 < NROWS_P;
            int idx = head ? idx2 : idx2 - NROWS_P;
            int b = idx / PP;
            unsigned rec = (unsigned)cur;
            int s = head ? ((rec >> 8) & 0x7F) : (rec & 0xFF);
            src4 = sr4 + ((size_t)(b * EE + s)) * D4;
            dst4 = (f32x4*)(head ? out6 : out7) + (size_t)idx * D4;
        } else {
            int j2 = row - (NROWS_W + 2 * NROWS_P);
            int b = j2 / MP;
            valid = (cur >= 0);
            src4 = te4 + ((size_t)(b * SS + (valid ? cur : 0))) * D4;
            dst4 = (f32x4*)out0 + (size_t)j2 * D4;
            stream_src = true;
        }
        #pragma unroll
        for (int k = 0; k < 3; ++k) {
            f32x4 v = (f32x4)(0.0f);
            if (valid) {
                v = stream_src ? __builtin_nontemporal_load(&src4[lane + 64 * k])
                               : src4[lane + 64 * k];
            }
            dst4[lane + 64 * k] = v;
        }
    }
}

extern "C" void kernel_launch(void* const* d_in, const int* in_sizes, int n_in,
                              void* d_out, int out_size, void* d_ws, size_t ws_size,
                              hipStream_t stream) {
    const float* te   = (const float*)d_in[0];  // token_embeds (B,S,D)
    const float* adj  = (const float*)d_in[1];  // adj (B,E,E)
    const float* sr   = (const float*)d_in[2];  // span_rep (B,E,D)
    const int*   ids  = (const int*)d_in[3];    // input_ids (B,S)
    // d_in[4] attention_mask: unused
    const int*   tlen = (const int*)d_in[5];    // text_lengths (B,1)
    const int*   wm   = (const int*)d_in[6];    // words_mask (B,S)
    float* out = (float*)d_out;

    size_t off0 = 0;
    size_t off1 = off0 + (size_t)BB * MP * DD;   // prompts_embedding
    size_t off2 = off1 + (size_t)BB * MP;        // prompts_mask
    size_t off3 = off2 + (size_t)BB * MT * DD;   // words_embedding
    size_t off4 = off3 + (size_t)BB * MT;        // word_mask
    size_t off5 = off4 + (size_t)BB * PP * 2;    // pair_idx
    size_t off6 = off5 + (size_t)BB * PP;        // pair_mask
    size_t off7 = off6 + (size_t)BB * PP * DD;   // head_rep -> tail_rep

    int* wordpos = (int*)d_ws;                   // B*MT
    int* pairrec = wordpos + BB * MT;            // B*PP
    int* pos     = pairrec + BB * PP;            // B*MP

    k_prep<<<24, 256, 0, stream>>>(ids, adj, wm, tlen,
                                   out + off1, out + off3, out + off4, out + off5,
                                   wordpos, pairrec, pos);
    k_gather<<<2048, 256, 0, stream>>>(te, sr, wordpos, pairrec, pos,
                                       out + off0, out + off2,
                                       out + off6, out + off7);
}